// Round 4
// baseline (440.707 us; speedup 1.0000x reference)
//
#include <hip/hip_runtime.h>

typedef unsigned short u16;
typedef __attribute__((ext_vector_type(8))) short bf16x8;
typedef __attribute__((ext_vector_type(4))) float f32x4;

struct __align__(8) u16x4_t { u16 x, y, z, w; };

__device__ __forceinline__ float b2f(u16 b) {
  union { unsigned u; float f; } v; v.u = ((unsigned)b) << 16; return v.f;
}
__device__ __forceinline__ u16 f2b(float f) {
  union { float f; unsigned u; } v; v.f = f;
  unsigned r = v.u + 0x7fffu + ((v.u >> 16) & 1u);
  return (u16)(r >> 16);
}
// pack two f32 -> bf16x2 (round half-up): 2 adds + 1 v_perm
__device__ __forceinline__ unsigned pk2(float x, float y) {
  union { float f; unsigned u; } a, b; a.f = x; b.f = y;
  return __builtin_amdgcn_perm(b.u + 0x8000u, a.u + 0x8000u, 0x07060302u);
}
__device__ __forceinline__ bf16x8 pack8(float4 lo, float4 hi) {
  union { bf16x8 v; unsigned u[4]; } t;
  t.u[0] = pk2(lo.x, lo.y); t.u[1] = pk2(lo.z, lo.w);
  t.u[2] = pk2(hi.x, hi.y); t.u[3] = pk2(hi.z, hi.w);
  return t.v;
}

// ---------------- fused: weight cvt (blocks 0..447) + mask/mlist build (448..545) ----------------
__global__ void init_misc(const float* __restrict__ Wp, const float* __restrict__ Wi,
                          const float* __restrict__ Wh, u16* __restrict__ wb,
                          const int* __restrict__ main_idx, int* __restrict__ mask,
                          int* __restrict__ mlist, int* __restrict__ cpos,
                          int* __restrict__ mcount, int nMain) {
  int b = blockIdx.x;
  if (b < 448) {
    int t = b * 256 + threadIdx.x;      // [0, 114688)
    const float* src; int o;
    if (t < 16384)      { src = Wp; o = t; }
    else if (t < 65536) { src = Wi; o = t - 16384; }
    else                { src = Wh; o = t - 65536; }
    float4 v = ((const float4*)src)[o];
    u16x4_t q;
    q.x = f2b(v.x); q.y = f2b(v.y); q.z = f2b(v.z); q.w = f2b(v.w);
    ((u16x4_t*)wb)[t] = q;
  } else {
    int t = (b - 448) * 256 + threadIdx.x;
    if (t < nMain) {
      int o = main_idx[t];
      if (atomicCAS(&mask[o], 0, 1) == 0) {
        int i = atomicAdd(mcount, 1);
        mlist[i] = o;
        cpos[o] = i;
      }
    }
  }
}

// ---------------- masked degree count ----------------
__global__ void count_edges(const int* __restrict__ obj_idx, const int* __restrict__ mask,
                            int* __restrict__ deg, int n) {
  int e = blockIdx.x * 256 + threadIdx.x;
  if (e >= n) return;
  int o = obj_idx[e];
  if (mask[o]) atomicAdd(&deg[o], 1);
}

// ---------------- segment allocation: wave-scan + one atomic per wave; also builds rrows ----------------
__global__ __launch_bounds__(256)
void alloc_offs(const int* __restrict__ mlist, const int* __restrict__ mcount,
                const int* __restrict__ deg, int* __restrict__ offs,
                int* __restrict__ tcur, int* __restrict__ rrows, int Mpad) {
  int i = blockIdx.x * 256 + threadIdx.x;
  int lane = threadIdx.x & 63;
  int mc = *mcount;
  if (i < Mpad) rrows[i] = (i < mc) ? mlist[i] : 0;
  int o = (i < mc) ? mlist[i] : 0;
  int d = (i < mc) ? deg[o] : 0;
  int x = d;
#pragma unroll
  for (int s = 1; s < 64; s <<= 1) {
    int y = __shfl_up(x, s, 64);
    if (lane >= s) x += y;
  }
  int wt = __shfl(x, 63, 64);
  int base = 0;
  if (lane == 63 && wt > 0) base = atomicAdd(tcur, wt);
  base = __shfl(base, 63, 64);
  if (i < mc) offs[o] = base + (x - d);
}

__global__ void fill_edges(const int* __restrict__ obj_idx, const int* __restrict__ evt_idx,
                           const int* __restrict__ mask, const int* __restrict__ offs,
                           int* __restrict__ cursor, int* __restrict__ elist, int n) {
  int e = blockIdx.x * 256 + threadIdx.x;
  if (e >= n) return;
  int o = obj_idx[e];
  if (!mask[o]) return;
  int pos = atomicAdd(&cursor[o], 1);
  elist[offs[o] + pos] = evt_idx[e];
}

// ---------------- register-accumulated scatter-mean, compacted output ----------------
__global__ __launch_bounds__(256)
void accum_prof(const u16* __restrict__ P, const int* __restrict__ elist,
                const int* __restrict__ offs, const int* __restrict__ deg,
                const int* __restrict__ mlist, const int* __restrict__ mcount,
                u16* __restrict__ prof, int Mpad) {
  const int wave = threadIdx.x >> 6;
  const int lane = threadIdx.x & 63;
  const int i = blockIdx.x * 4 + wave;
  if (i >= Mpad) return;
  const int mc = *mcount;
  float a0 = 0.f, a1 = 0.f, a2 = 0.f, a3 = 0.f;
  int d = 0;
  if (i < mc) {
    const int o = mlist[i];
    const int off = offs[o];
    d = deg[o];
    int j = 0;
    for (; j + 1 < d; j += 2) {
      int e0 = elist[off + j], e1 = elist[off + j + 1];
      u16x4_t p0 = *(const u16x4_t*)(P + (size_t)e0 * 256 + lane * 4);
      u16x4_t p1 = *(const u16x4_t*)(P + (size_t)e1 * 256 + lane * 4);
      a0 += b2f(p0.x) + b2f(p1.x);
      a1 += b2f(p0.y) + b2f(p1.y);
      a2 += b2f(p0.z) + b2f(p1.z);
      a3 += b2f(p0.w) + b2f(p1.w);
    }
    if (j < d) {
      int e0 = elist[off + j];
      u16x4_t p0 = *(const u16x4_t*)(P + (size_t)e0 * 256 + lane * 4);
      a0 += b2f(p0.x); a1 += b2f(p0.y); a2 += b2f(p0.z); a3 += b2f(p0.w);
    }
  }
  float s = 1.f / fmaxf((float)d, 1.f);
  u16x4_t ov;
  ov.x = f2b(a0 * s); ov.y = f2b(a1 * s); ov.z = f2b(a2 * s); ov.w = f2b(a3 * s);
  *(u16x4_t*)(prof + (size_t)i * 256 + lane * 4) = ov;
}

// ---------------- MFMA GEMM, A-in-registers, B-panel-in-LDS (K=256 fixed) ----------------
// C[M,N] = A[M,256] @ B[N,256]^T + bias. AF32: A is fp32, packed in-register.
// B panel (128 x 256 bf16 = 64 KB) staged ONCE via global_load_lds with XOR-swizzled
// source chunks; K-loop has no barriers -> compiler pipelines with fine vmcnt/lgkm.
template<int RELU, int GATHER, int AF32>
__global__ __launch_bounds__(256, 2)
void gemm_rs(const u16* __restrict__ Ab, const float* __restrict__ Af,
             const u16* __restrict__ B, const float* __restrict__ bias,
             u16* __restrict__ C, const int* __restrict__ ridx, int M, int N) {
  __shared__ u16 lB[128 * 256];   // 64 KB
  const int tid  = threadIdx.x;
  const int lane = tid & 63;
  const int wave = tid >> 6;
  const int m0 = blockIdx.x * 128;
  const int n0 = blockIdx.y * 128;
  const int mR = (wave & 1) * 64;
  const int nC = (wave >> 1) * 64;
  const int la15 = lane & 15;
  const int kof  = (lane >> 4) * 8;

  // A row indices (per lane, fixed for whole kernel)
  int arow[4];
#pragma unroll
  for (int i = 0; i < 4; ++i) {
    int r = m0 + mR + i * 16 + la15;
    if (GATHER) arow[i] = ridx[r];
    else        arow[i] = (r < M) ? r : (M - 1);
  }

  // stage B panel: 4096 x 16B segments; source chunk index XOR-swizzled so that
  // LDS chunk position cp holds logical chunk (cp&24)|((cp^row)&7)
#pragma unroll
  for (int s = 0; s < 16; ++s) {
    int seg = s * 256 + tid;
    int row = seg >> 5;
    int cp  = seg & 31;
    int c   = (cp & 24) | ((cp ^ row) & 7);
    const u16* gB = B + (size_t)(n0 + row) * 256 + c * 8;
    __builtin_amdgcn_global_load_lds(
        (const __attribute__((address_space(1))) void*)gB,
        (__attribute__((address_space(3))) void*)(lB + s * 2048 + wave * 512),
        16, 0, 0);
  }
  __syncthreads();

  f32x4 acc[4][4] = {};

  const float* ap[4];
  const u16*   abp[4];
  float4 c0[4], c1[4];
  if (AF32) {
#pragma unroll
    for (int i = 0; i < 4; ++i) {
      ap[i] = Af + (size_t)arow[i] * 256 + kof;
      c0[i] = *(const float4*)(ap[i]);
      c1[i] = *(const float4*)(ap[i] + 4);
    }
  } else {
#pragma unroll
    for (int i = 0; i < 4; ++i) abp[i] = Ab + (size_t)arow[i] * 256 + kof;
  }

#pragma unroll
  for (int ks = 0; ks < 8; ++ks) {
    bf16x8 af[4], bfr[4];
    if (AF32) {
      float4 n0v[4], n1v[4];
      if (ks < 7) {
#pragma unroll
        for (int i = 0; i < 4; ++i) {
          n0v[i] = *(const float4*)(ap[i] + (ks + 1) * 32);
          n1v[i] = *(const float4*)(ap[i] + (ks + 1) * 32 + 4);
        }
      }
#pragma unroll
      for (int i = 0; i < 4; ++i) af[i] = pack8(c0[i], c1[i]);
      if (ks < 7) {
#pragma unroll
        for (int i = 0; i < 4; ++i) { c0[i] = n0v[i]; c1[i] = n1v[i]; }
      }
    } else {
#pragma unroll
      for (int i = 0; i < 4; ++i)
        af[i] = *(const bf16x8*)(abp[i] + ks * 32);
    }
#pragma unroll
    for (int j = 0; j < 4; ++j) {
      int rj = nC + j * 16 + la15;
      int c  = ks * 4 + (lane >> 4);
      int cp = (c & 24) | ((c ^ rj) & 7);
      bfr[j] = *(const bf16x8*)(lB + rj * 256 + cp * 8);
    }
#pragma unroll
    for (int i = 0; i < 4; ++i)
#pragma unroll
      for (int j = 0; j < 4; ++j)
        acc[i][j] = __builtin_amdgcn_mfma_f32_16x16x32_bf16(af[i], bfr[j], acc[i][j], 0, 0, 0);
  }

  // C/D layout: col=lane&15, row=(lane>>4)*4+reg (verified m89/m91)
  const int crow = (lane >> 4) * 4;
#pragma unroll
  for (int i = 0; i < 4; ++i) {
#pragma unroll
    for (int j = 0; j < 4; ++j) {
      int col = n0 + nC + j * 16 + la15;
      float bv = bias[col];
#pragma unroll
      for (int q = 0; q < 4; ++q) {
        int row = m0 + mR + i * 16 + crow + q;
        if (row < M) {
          float v = acc[i][j][q] + bv;
          if (RELU) v = fmaxf(v, 0.f);
          C[(size_t)row * N + col] = f2b(v);
        }
      }
    }
  }
}

// ---------------- GRU gates + masked blend (float4-vectorized; 4 rows / block) ----------------
__global__ __launch_bounds__(256)
void gate_out(const u16* __restrict__ gi, const u16* __restrict__ gh,
              const float* __restrict__ objX, const int* __restrict__ mask,
              const int* __restrict__ cpos, float* __restrict__ out, int nObj) {
  const int wave = threadIdx.x >> 6;
  const int lane = threadIdx.x & 63;
  const int row = blockIdx.x * 4 + wave;
  if (row >= nObj) return;
  float4 x4 = *(const float4*)(objX + (size_t)row * 256 + lane * 4);
  float4 r4 = x4;
  if (mask[row]) {
    size_t b = (size_t)cpos[row] * 768 + lane * 4;
    u16x4_t ir = *(const u16x4_t*)(gi + b);
    u16x4_t iz = *(const u16x4_t*)(gi + b + 256);
    u16x4_t in_ = *(const u16x4_t*)(gi + b + 512);
    u16x4_t hr = *(const u16x4_t*)(gh + b);
    u16x4_t hz = *(const u16x4_t*)(gh + b + 256);
    u16x4_t hn = *(const u16x4_t*)(gh + b + 512);
    float xs[4] = {x4.x, x4.y, x4.z, x4.w};
    u16 irs[4] = {ir.x, ir.y, ir.z, ir.w};
    u16 izs[4] = {iz.x, iz.y, iz.z, iz.w};
    u16 ins[4] = {in_.x, in_.y, in_.z, in_.w};
    u16 hrs[4] = {hr.x, hr.y, hr.z, hr.w};
    u16 hzs[4] = {hz.x, hz.y, hz.z, hz.w};
    u16 hns[4] = {hn.x, hn.y, hn.z, hn.w};
    float rs[4];
#pragma unroll
    for (int q = 0; q < 4; ++q) {
      float r = 1.f / (1.f + __expf(-(b2f(irs[q]) + b2f(hrs[q]))));
      float z = 1.f / (1.f + __expf(-(b2f(izs[q]) + b2f(hzs[q]))));
      float a = b2f(ins[q]) + r * b2f(hns[q]);
      float n = 1.f - 2.f / (__expf(2.f * a) + 1.f);
      rs[q] = (1.f - z) * n + z * xs[q];
    }
    r4.x = rs[0]; r4.y = rs[1]; r4.z = rs[2]; r4.w = rs[3];
  }
  *(float4*)(out + (size_t)row * 256 + lane * 4) = r4;
}

// ---------------- workspace layout (bytes) ----------------
//           0  P      51,200,000  (dead after accum) -> gi reuse (38,535,168)
//  51,200,000  gh     38,535,168
//  89,735,168  prof   12,845,056  (25088 x 256 bf16 compact)
// 102,580,224  wb        917,504  (wpb|wib|whb)
// 103,497,728  deg       200,000  \
// 103,697,728  cursor    200,000   |  one memset zeroes
// 103,897,728  mask      200,000   |  [103,497,728 .. 104,097,856)
// 104,097,728  mcount         64   |
// 104,097,792  tcur           64  /
// 104,097,856  cpos      200,000
// 104,297,856  offs      200,000
// 104,497,856  mlist     100,352
// 104,598,208  rrows     100,352
// 104,698,560  elist   2,000,000
// total 106,698,560

extern "C" void kernel_launch(void* const* d_in, const int* in_sizes, int n_in,
                              void* d_out, int out_size, void* d_ws, size_t ws_size,
                              hipStream_t stream) {
  const float* objX   = (const float*)d_in[0];
  const float* evtX   = (const float*)d_in[1];
  const int* obj_idx  = (const int*)d_in[2];
  const int* evt_idx  = (const int*)d_in[3];
  const int* main_idx = (const int*)d_in[4];
  const float* Wp = (const float*)d_in[5];
  const float* bp = (const float*)d_in[6];
  const float* Wi = (const float*)d_in[7];
  const float* bi = (const float*)d_in[8];
  const float* Wh = (const float*)d_in[9];
  const float* bh = (const float*)d_in[10];

  const int nObj  = in_sizes[0] / 256;   // 50000
  const int nEvt  = in_sizes[1] / 256;   // 100000
  const int nEdge = in_sizes[2];         // 500000
  const int nMain = in_sizes[4];         // 25000
  const int Mpad  = ((nMain + 127) / 128) * 128;  // 25088

  char* ws = (char*)d_ws;
  u16*   P     = (u16*)(ws + 0);
  u16*   gi    = (u16*)(ws + 0);
  u16*   gh    = (u16*)(ws + 51200000);
  u16*   prof  = (u16*)(ws + 89735168);
  u16*   wb    = (u16*)(ws + 102580224);
  u16*   wpb   = wb;
  u16*   wib   = wb + 65536;
  u16*   whb   = wb + 262144;
  int*   deg   = (int*)(ws + 103497728);
  int*   cursor= (int*)(ws + 103697728);
  int*   mask  = (int*)(ws + 103897728);
  int*   mcount= (int*)(ws + 104097728);
  int*   tcur  = (int*)(ws + 104097792);
  int*   cpos  = (int*)(ws + 104097856);
  int*   offs  = (int*)(ws + 104297856);
  int*   mlist = (int*)(ws + 104497856);
  int*   rrows = (int*)(ws + 104598208);
  int*   elist = (int*)(ws + 104698560);
  float* out   = (float*)d_out;

  // zero deg/cursor/mask/mcount/tcur in one shot
  hipMemsetAsync(ws + 103497728, 0, 600128, stream);

  init_misc<<<546, 256, 0, stream>>>(Wp, Wi, Wh, wb, main_idx, mask, mlist, cpos, mcount, nMain);

  // P = relu(evtX @ Wp^T + bp)   [100000 x 256], A fp32 in registers
  gemm_rs<1, 0, 1><<<dim3((nEvt + 127) / 128, 2), 256, 0, stream>>>(
      nullptr, evtX, wpb, bp, P, nullptr, nEvt, 256);

  count_edges<<<(nEdge + 255) / 256, 256, 0, stream>>>(obj_idx, mask, deg, nEdge);
  alloc_offs<<<Mpad / 256, 256, 0, stream>>>(mlist, mcount, deg, offs, tcur, rrows, Mpad);
  fill_edges<<<(nEdge + 255) / 256, 256, 0, stream>>>(obj_idx, evt_idx, mask, offs, cursor, elist, nEdge);

  accum_prof<<<(Mpad + 3) / 4, 256, 0, stream>>>(P, elist, offs, deg, mlist, mcount, prof, Mpad);

  // compact GRU GEMMs [25088 x 768]
  gemm_rs<0, 0, 0><<<dim3(Mpad / 128, 6), 256, 0, stream>>>(
      prof, nullptr, wib, bi, gi, nullptr, Mpad, 768);
  gemm_rs<0, 1, 1><<<dim3(Mpad / 128, 6), 256, 0, stream>>>(
      nullptr, objX, whb, bh, gh, rrows, Mpad, 768);

  gate_out<<<(nObj + 3) / 4, 256, 0, stream>>>(gi, gh, objX, mask, cpos, out, nObj);
}